// Round 1
// baseline (1998.212 us; speedup 1.0000x reference)
//
#include <hip/hip_runtime.h>
#include <math.h>

#define BATCH 8
#define CH    256
#define HWPIX 4096
#define CQK_  32
#define TQ    64
#define TM    32
#define SSTR  36    // s_s row stride (dwords): 32 m + pad, 16B-aligned rows
#define VSTR  260   // v_s row stride (dwords): 256 c + pad, 16B-aligned rows

// out[b][o][n] = bias[o] + sum_c W[o][c] * f[b][c][n]
// grid: (HW/64, O/32, B), block: (64,4); each thread produces 8 consecutive o
__global__ __launch_bounds__(256) void proj_kernel(
    const float* __restrict__ f, const float* __restrict__ W,
    const float* __restrict__ bias, float* __restrict__ out, int O)
{
  const int n  = blockIdx.x * 64 + threadIdx.x;
  const int o0 = (blockIdx.y * 4 + threadIdx.y) * 8;
  const int b  = blockIdx.z;
  const float* fb = f + (size_t)b * CH * HWPIX + n;
  float acc[8];
#pragma unroll
  for (int j = 0; j < 8; ++j) acc[j] = bias[o0 + j];
  for (int c = 0; c < CH; ++c) {
    const float fv = fb[(size_t)c * HWPIX];
#pragma unroll
    for (int j = 0; j < 8; ++j)
      acc[j] = fmaf(fv, W[(o0 + j) * CH + c], acc[j]);
  }
  float* ob = out + ((size_t)b * O + o0) * HWPIX + n;
#pragma unroll
  for (int j = 0; j < 8; ++j) ob[(size_t)j * HWPIX] = acc[j];
}

// Flash-style fused attention. Block = (q-tile of 64, batch). 256 threads.
// O accumulator: thread (cg=t&31, qg=t>>5) owns c in cg*8+[0,8), q in qg*8+[0,8).
__global__ __launch_bounds__(256) void attn_kernel(
    const float* __restrict__ q, const float* __restrict__ k,
    const float* __restrict__ v, float* __restrict__ out)
{
  __shared__ float q_s[CQK_ * TQ];        // [c][q]   8 KB
  __shared__ float s_s[TQ * SSTR];        // [q][m]   9 KB
  __shared__ float v_s[TM * VSTR];        // [m][c]  33 KB (reused for epilogue transpose)
  __shared__ float M_s[TQ], L_s[TQ], A_s[TQ];

  const int t  = threadIdx.x;
  const int b  = blockIdx.y;
  const int q0 = blockIdx.x * TQ;

  for (int idx = t; idx < CQK_ * TQ; idx += 256) {
    const int c = idx >> 6, qq = idx & 63;
    q_s[c * TQ + qq] = q[((size_t)b * CQK_ + c) * HWPIX + q0 + qq];
  }
  if (t < TQ) { M_s[t] = -1e30f; L_s[t] = 0.0f; }
  __syncthreads();

  const int cg = t & 31;
  const int qg = t >> 5;
  float oacc[8][8];
#pragma unroll
  for (int i = 0; i < 8; ++i)
#pragma unroll
    for (int j = 0; j < 8; ++j) oacc[i][j] = 0.0f;

  for (int m0 = 0; m0 < HWPIX; m0 += TM) {
    // ---- phase 1: scores s[q][m] = sum_c q_s[c][q] * k[c][m] ----
    {
      const int m  = t & 31;       // key within tile (coalesced k loads)
      const int qs = t >> 5;       // 8 groups x 8 queries
      float sc[8];
#pragma unroll
      for (int i = 0; i < 8; ++i) sc[i] = 0.0f;
      const float* kb = k + (size_t)b * CQK_ * HWPIX + m0 + m;
      for (int c = 0; c < CQK_; ++c) {
        const float kv = kb[(size_t)c * HWPIX];
        const float* qrow = &q_s[c * TQ + qs * 8];
#pragma unroll
        for (int i = 0; i < 8; ++i) sc[i] = fmaf(qrow[i], kv, sc[i]);
      }
#pragma unroll
      for (int i = 0; i < 8; ++i) s_s[(qs * 8 + i) * SSTR + m] = sc[i];
    }
    // ---- stage V tile: v[b][c][m0+mm] -> v_s[mm][c] ----
    for (int idx = t; idx < TM * CH; idx += 256) {
      const int mm = idx & (TM - 1);
      const int c  = idx >> 5;
      v_s[mm * VSTR + c] = v[((size_t)b * CH + c) * HWPIX + m0 + mm];
    }
    __syncthreads();
    // ---- online softmax over this tile (thread t: row t>>2, m-chunk t&3) ----
    {
      const int qq = t >> 2, ch = t & 3;
      float* srow = &s_s[qq * SSTR + ch * 8];
      float sv[8];
#pragma unroll
      for (int i = 0; i < 8; ++i) sv[i] = srow[i];
      float mx = sv[0];
#pragma unroll
      for (int i = 1; i < 8; ++i) mx = fmaxf(mx, sv[i]);
      mx = fmaxf(mx, __shfl_xor(mx, 1));
      mx = fmaxf(mx, __shfl_xor(mx, 2));
      const float Mold = M_s[qq];       // safe: Mnew identical even if racy (see note)
      const float Mnew = fmaxf(Mold, mx);
      float sum = 0.0f;
#pragma unroll
      for (int i = 0; i < 8; ++i) { sv[i] = __expf(sv[i] - Mnew); sum += sv[i]; }
      sum += __shfl_xor(sum, 1);
      sum += __shfl_xor(sum, 2);
#pragma unroll
      for (int i = 0; i < 8; ++i) srow[i] = sv[i];
      if (ch == 0) {
        // note: if ch!=0 lanes read M_s after this write, fmaxf(Mnew,mx)==Mnew, same result
        const float al = __expf(Mold - Mnew);
        M_s[qq] = Mnew;
        L_s[qq] = L_s[qq] * al + sum;
        A_s[qq] = al;
      }
    }
    __syncthreads();
    // ---- AV: oacc[c][q] = oacc*alpha + sum_m v[c][m] * p[q][m] ----
    {
      float al[8];
#pragma unroll
      for (int j = 0; j < 8; ++j) al[j] = A_s[qg * 8 + j];
#pragma unroll
      for (int i = 0; i < 8; ++i)
#pragma unroll
        for (int j = 0; j < 8; ++j) oacc[i][j] *= al[j];

      for (int m4 = 0; m4 < TM; m4 += 4) {
        float4 pv[8];
#pragma unroll
        for (int j = 0; j < 8; ++j)
          pv[j] = *(const float4*)&s_s[(qg * 8 + j) * SSTR + m4];
#pragma unroll
        for (int mm = 0; mm < 4; ++mm) {
          const float4 va = *(const float4*)&v_s[(m4 + mm) * VSTR + cg * 8];
          const float4 vb = *(const float4*)&v_s[(m4 + mm) * VSTR + cg * 8 + 4];
          const float vv[8] = {va.x, va.y, va.z, va.w, vb.x, vb.y, vb.z, vb.w};
#pragma unroll
          for (int i = 0; i < 8; ++i)
#pragma unroll
            for (int j = 0; j < 8; ++j)
              oacc[i][j] = fmaf(vv[i], ((const float*)&pv[j])[mm], oacc[i][j]);
        }
      }
    }
    __syncthreads();
  }

  // ---- epilogue: O /= L, transpose 64c x 64q chunks through LDS, coalesced store ----
  float rl[8];
#pragma unroll
  for (int j = 0; j < 8; ++j) rl[j] = 1.0f / L_s[qg * 8 + j];
  for (int kc = 0; kc < 4; ++kc) {
    if ((cg >> 3) == kc) {
      const int cl0 = (cg & 7) * 8;
#pragma unroll
      for (int i = 0; i < 8; ++i)
#pragma unroll
        for (int j = 0; j < 8; ++j)
          v_s[(cl0 + i) * 68 + qg * 8 + j] = oacc[i][j] * rl[j];
    }
    __syncthreads();
    {
      const int qq = t & 63;
      const int cr = t >> 6;
#pragma unroll
      for (int r = 0; r < 16; ++r) {
        const int cl = cr * 16 + r;
        out[((size_t)b * CH + kc * 64 + cl) * HWPIX + q0 + qq] = v_s[cl * 68 + qq];
      }
    }
    __syncthreads();
  }
}

extern "C" void kernel_launch(void* const* d_in, const int* in_sizes, int n_in,
                              void* d_out, int out_size, void* d_ws, size_t ws_size,
                              hipStream_t stream)
{
  const float* f1 = (const float*)d_in[0];
  const float* f2 = (const float*)d_in[1];
  const float* f3 = (const float*)d_in[2];
  const float* wq = (const float*)d_in[3];
  const float* bq = (const float*)d_in[4];
  const float* wk = (const float*)d_in[5];
  const float* bk = (const float*)d_in[6];
  const float* wv = (const float*)d_in[7];
  const float* bv = (const float*)d_in[8];
  float* outp = (float*)d_out;

  // workspace: q [8][32][4096] | k [8][32][4096] | v [8][256][4096]  (42 MB fp32)
  float* qw = (float*)d_ws;
  float* kw = qw + (size_t)BATCH * CQK_ * HWPIX;
  float* vw = kw + (size_t)BATCH * CQK_ * HWPIX;

  dim3 pb(64, 4);
  proj_kernel<<<dim3(HWPIX / 64, 1, BATCH), pb, 0, stream>>>(f1, wq, bq, qw, CQK_);
  proj_kernel<<<dim3(HWPIX / 64, 1, BATCH), pb, 0, stream>>>(f2, wk, bk, kw, CQK_);
  proj_kernel<<<dim3(HWPIX / 64, 8, BATCH), pb, 0, stream>>>(f3, wv, bv, vw, CH);
  attn_kernel<<<dim3(HWPIX / TQ, BATCH), 256, 0, stream>>>(qw, kw, vw, outp);
}

// Round 2
// 522.908 us; speedup vs baseline: 3.8213x; 3.8213x over previous
//
#include <hip/hip_runtime.h>
#include <math.h>

#define BATCH 8
#define CH    256
#define HWPIX 4096
#define CQK_  32

typedef __bf16 bf16x8 __attribute__((ext_vector_type(8)));
typedef float  f32x4  __attribute__((ext_vector_type(4)));

// ---- Q/K projection: out[b][o][n] -> stored TRANSPOSED as outT[b][n][32] bf16
// grid (64, 8), block 256 = (64 n, 4 og); thread computes 8 o for its n.
__global__ __launch_bounds__(256) void proj_qk_kernel(
    const float* __restrict__ f, const float* __restrict__ W,
    const float* __restrict__ bias, __bf16* __restrict__ outT)
{
  __shared__ float fs[64 * 64];
  const int t  = threadIdx.x;
  const int n  = t & 63;
  const int og = __builtin_amdgcn_readfirstlane(t >> 6);
  const int o0 = og * 8;
  const int b  = blockIdx.y;
  const int n0 = blockIdx.x * 64;

  float acc[8];
#pragma unroll
  for (int j = 0; j < 8; ++j) acc[j] = bias[o0 + j];

  for (int c0 = 0; c0 < CH; c0 += 64) {
#pragma unroll
    for (int k = 0; k < 16; ++k) {
      const int c = og * 16 + k;
      fs[c * 64 + n] = f[((size_t)b * CH + c0 + c) * HWPIX + n0 + n];
    }
    __syncthreads();
    for (int c = 0; c < 64; ++c) {
      const float fv = fs[c * 64 + n];
#pragma unroll
      for (int j = 0; j < 8; ++j)
        acc[j] = fmaf(fv, W[(o0 + j) * CH + c0 + c], acc[j]);
    }
    __syncthreads();
  }
  bf16x8 pk;
#pragma unroll
  for (int j = 0; j < 8; ++j) pk[j] = (__bf16)acc[j];
  *(bf16x8*)(outT + ((size_t)b * HWPIX + n0 + n) * CQK_ + o0) = pk;
}

// ---- V projection: outv[b][c][hw] bf16 (native layout).
// grid (64, 8), block 256 = (64 n, 4 og); thread computes 64 o for its n.
__global__ __launch_bounds__(256) void proj_v_kernel(
    const float* __restrict__ f, const float* __restrict__ W,
    const float* __restrict__ bias, __bf16* __restrict__ outv)
{
  __shared__ float fs[64 * 64];
  const int t  = threadIdx.x;
  const int n  = t & 63;
  const int og = __builtin_amdgcn_readfirstlane(t >> 6);
  const int obch = og * 64;
  const int b  = blockIdx.y;
  const int n0 = blockIdx.x * 64;

  float acc[64];
#pragma unroll
  for (int j = 0; j < 64; ++j) acc[j] = bias[obch + j];

  for (int c0 = 0; c0 < CH; c0 += 64) {
#pragma unroll
    for (int k = 0; k < 16; ++k) {
      const int c = og * 16 + k;
      fs[c * 64 + n] = f[((size_t)b * CH + c0 + c) * HWPIX + n0 + n];
    }
    __syncthreads();
    for (int c = 0; c < 64; ++c) {
      const float fv = fs[c * 64 + n];
#pragma unroll
      for (int j = 0; j < 64; ++j)
        acc[j] = fmaf(fv, W[(obch + j) * CH + c0 + c], acc[j]);
    }
    __syncthreads();
  }
#pragma unroll
  for (int j = 0; j < 64; ++j)
    outv[((size_t)b * CH + obch + j) * HWPIX + n0 + n] = (__bf16)acc[j];
}

// ---- Fused attention, MFMA 16x16x32 bf16, no-max online softmax (sum only).
// grid 512: b = bx&7 (XCD-pinned), q-tile = bx>>3 (64 q). block 256 = 4 waves.
// Wave w: score rows q in [16w,16w+16); AV channels c in [64w, 64w+64).
__global__ __launch_bounds__(256, 2) void attn_kernel(
    const __bf16* __restrict__ qT, const __bf16* __restrict__ kT,
    const __bf16* __restrict__ vv, float* __restrict__ out)
{
  __shared__ __align__(16) __bf16 p_s[64 * 72];  // [q][m], stride 72 bf16
  __shared__ float L_s[64];

  const int t    = threadIdx.x;
  const int w    = __builtin_amdgcn_readfirstlane(t >> 6);
  const int lane = t & 63;
  const int q16  = lane & 15;
  const int quad = lane >> 4;

  const int b  = blockIdx.x & 7;
  const int q0 = (blockIdx.x >> 3) * 64;

  const __bf16* kTb = kT + (size_t)b * HWPIX * CQK_;
  const __bf16* vbp = vv + ((size_t)b * CH + 64 * w) * HWPIX;

  // Q A-fragment, loaded once: Q[q = q0+16w+q16][c = quad*8 + j]
  const bf16x8 qfrag =
      *(const bf16x8*)(qT + ((size_t)b * HWPIX + q0 + 16 * w + q16) * CQK_ + quad * 8);

  f32x4 oacc[4][4];
#pragma unroll
  for (int i = 0; i < 4; ++i)
#pragma unroll
    for (int j = 0; j < 4; ++j)
      oacc[i][j] = (f32x4){0.f, 0.f, 0.f, 0.f};
  float Lp[4] = {0.f, 0.f, 0.f, 0.f};

  // K B-fragments for m0 = 0 (prefetched; rotated each iteration)
  bf16x8 kf[4];
#pragma unroll
  for (int mt = 0; mt < 4; ++mt)
    kf[mt] = *(const bf16x8*)(kTb + (size_t)(16 * mt + q16) * CQK_ + quad * 8);

  for (int m0 = 0; m0 < HWPIX; m0 += 64) {
    // ---- scores: S[16q x 16m] per mt, one MFMA each (K-dim = 32 = CQK)
    f32x4 S[4];
#pragma unroll
    for (int mt = 0; mt < 4; ++mt)
      S[mt] = __builtin_amdgcn_mfma_f32_16x16x32_bf16(
          qfrag, kf[mt], (f32x4){0.f, 0.f, 0.f, 0.f}, 0, 0, 0);

    // ---- V A-fragments for this m-tile (global, L2-resident; issued early)
    bf16x8 vf[4][2];
#pragma unroll
    for (int ct = 0; ct < 4; ++ct)
#pragma unroll
      for (int mh = 0; mh < 2; ++mh)
        vf[ct][mh] = *(const bf16x8*)(vbp + (size_t)(16 * ct + q16) * HWPIX
                                      + m0 + 32 * mh + quad * 8);

    // ---- exp, accumulate L, write P tile to LDS (bf16)
#pragma unroll
    for (int mt = 0; mt < 4; ++mt) {
#pragma unroll
      for (int r = 0; r < 4; ++r) {
        const float e = __expf(S[mt][r]);
        Lp[r] += e;
        p_s[(16 * w + quad * 4 + r) * 72 + 16 * mt + q16] = (__bf16)e;
      }
    }
    __syncthreads();

    // prefetch next iteration's K fragments (wraps harmlessly on last iter)
    const int mn = (m0 + 64) & (HWPIX - 1);
#pragma unroll
    for (int mt = 0; mt < 4; ++mt)
      kf[mt] = *(const bf16x8*)(kTb + (size_t)(mn + 16 * mt + q16) * CQK_ + quad * 8);

    // ---- P B-fragments from LDS: P[q = 16nt+q16][m = 32mh + quad*8 + j]
    bf16x8 pf[4][2];
#pragma unroll
    for (int nt = 0; nt < 4; ++nt)
#pragma unroll
      for (int mh = 0; mh < 2; ++mh)
        pf[nt][mh] = *(const bf16x8*)(&p_s[(16 * nt + q16) * 72 + 32 * mh + quad * 8]);

    // ---- AV: oacc[ct][nt] += V[16c x 32m] @ P^T[32m x 16q]
#pragma unroll
    for (int ct = 0; ct < 4; ++ct)
#pragma unroll
      for (int nt = 0; nt < 4; ++nt)
#pragma unroll
        for (int mh = 0; mh < 2; ++mh)
          oacc[ct][nt] = __builtin_amdgcn_mfma_f32_16x16x32_bf16(
              vf[ct][mh], pf[nt][mh], oacc[ct][nt], 0, 0, 0);
    __syncthreads();
  }

  // ---- finalize L: reduce partial sums across the 16 lanes of each row
#pragma unroll
  for (int r = 0; r < 4; ++r) {
    Lp[r] += __shfl_xor(Lp[r], 1);
    Lp[r] += __shfl_xor(Lp[r], 2);
    Lp[r] += __shfl_xor(Lp[r], 4);
    Lp[r] += __shfl_xor(Lp[r], 8);
  }
  if (q16 == 0) {
#pragma unroll
    for (int r = 0; r < 4; ++r) L_s[16 * w + quad * 4 + r] = Lp[r];
  }
  __syncthreads();

  float rinv[4];
#pragma unroll
  for (int nt = 0; nt < 4; ++nt) rinv[nt] = 1.0f / L_s[16 * nt + q16];

  float* ob = out + ((size_t)b * CH + 64 * w) * HWPIX + q0;
#pragma unroll
  for (int ct = 0; ct < 4; ++ct)
#pragma unroll
    for (int r = 0; r < 4; ++r)
#pragma unroll
      for (int nt = 0; nt < 4; ++nt)
        ob[(size_t)(16 * ct + quad * 4 + r) * HWPIX + 16 * nt + q16] =
            oacc[ct][nt][r] * rinv[nt];
}

extern "C" void kernel_launch(void* const* d_in, const int* in_sizes, int n_in,
                              void* d_out, int out_size, void* d_ws, size_t ws_size,
                              hipStream_t stream)
{
  const float* f1 = (const float*)d_in[0];
  const float* f2 = (const float*)d_in[1];
  const float* f3 = (const float*)d_in[2];
  const float* wq = (const float*)d_in[3];
  const float* bq = (const float*)d_in[4];
  const float* wk = (const float*)d_in[5];
  const float* bk = (const float*)d_in[6];
  const float* wv = (const float*)d_in[7];
  const float* bv = (const float*)d_in[8];
  float* outp = (float*)d_out;

  // workspace: qT [8][4096][32] | kT [8][4096][32] | v [8][256][4096]  (bf16, 20 MB)
  __bf16* qTw = (__bf16*)d_ws;
  __bf16* kTw = qTw + (size_t)BATCH * HWPIX * CQK_;
  __bf16* vw  = kTw + (size_t)BATCH * HWPIX * CQK_;

  proj_qk_kernel<<<dim3(64, 8), 256, 0, stream>>>(f1, wq, bq, qTw);
  proj_qk_kernel<<<dim3(64, 8), 256, 0, stream>>>(f2, wk, bk, kTw);
  proj_v_kernel <<<dim3(64, 8), 256, 0, stream>>>(f3, wv, bv, vw);
  attn_kernel   <<<dim3(512), 256, 0, stream>>>(qTw, kTw, vw, outp);
}

// Round 3
// 319.050 us; speedup vs baseline: 6.2630x; 1.6390x over previous
//
#include <hip/hip_runtime.h>
#include <math.h>

#define BATCH 8
#define CH    256
#define HWPIX 4096
#define CQK_  32

typedef __bf16 bf16x8 __attribute__((ext_vector_type(8)));
typedef __bf16 bf16x4 __attribute__((ext_vector_type(4)));
typedef __bf16 bf16x2 __attribute__((ext_vector_type(2)));
typedef float  f32x4  __attribute__((ext_vector_type(4)));

#define FS_STR 68   // LDS transpose-tile row stride in bf16 (136 B: 8B-aligned, 2-way banks)

// load a bf16x8 fragment from LDS as two 8B halves (rows only 8B-aligned)
static __device__ inline bf16x8 ld_frag(const __bf16* p) {
  bf16x4 lo = *(const bf16x4*)p;
  bf16x4 hi = *(const bf16x4*)(p + 4);
  return __builtin_shufflevector(lo, hi, 0, 1, 2, 3, 4, 5, 6, 7);
}

// load 8 consecutive fp32 from a W row, convert to bf16x8 fragment
static __device__ inline bf16x8 w_frag(const float* p) {
  const float4 a = *(const float4*)p;
  const float4 b = *(const float4*)(p + 4);
  bf16x8 r;
  r[0] = (__bf16)a.x; r[1] = (__bf16)a.y; r[2] = (__bf16)a.z; r[3] = (__bf16)a.w;
  r[4] = (__bf16)b.x; r[5] = (__bf16)b.y; r[6] = (__bf16)b.z; r[7] = (__bf16)b.w;
  return r;
}

// ---- Q/K projection (MFMA): outT[b][n][32] bf16.
// grid (64 n-tiles, 8 b), block 256 = 4 waves; wave w handles n rows [16w,16w+16).
__global__ __launch_bounds__(256) void proj_qk_mfma(
    const float* __restrict__ f, const float* __restrict__ W,
    const float* __restrict__ bias, __bf16* __restrict__ outT)
{
  __shared__ __align__(16) __bf16 f_s[64 * FS_STR];  // [n][cin] transposed tile
  const int t    = threadIdx.x;
  const int w    = __builtin_amdgcn_readfirstlane(t >> 6);
  const int lane = t & 63;
  const int q16  = lane & 15;
  const int quad = lane >> 4;
  const int b    = blockIdx.y;
  const int n0   = blockIdx.x * 64;
  const float* fb = f + (size_t)b * CH * HWPIX + n0;

  const float bo0 = bias[q16];
  const float bo1 = bias[16 + q16];

  f32x4 acc[2];
  acc[0] = (f32x4){0.f, 0.f, 0.f, 0.f};
  acc[1] = (f32x4){0.f, 0.f, 0.f, 0.f};

  for (int c0 = 0; c0 < CH; c0 += 64) {
    // stage f[c0..c0+64)[n0..n0+64) -> f_s[n][cin] bf16 (transposed)
    {
      const int n  = t & 63;
      const int cp = (t >> 6) * 2;
#pragma unroll
      for (int k = 0; k < 8; ++k) {
        const int cin = cp + k * 8;
        bf16x2 pk;
        pk[0] = (__bf16)fb[(size_t)(c0 + cin) * HWPIX + n];
        pk[1] = (__bf16)fb[(size_t)(c0 + cin + 1) * HWPIX + n];
        *(bf16x2*)&f_s[n * FS_STR + cin] = pk;
      }
    }
    __syncthreads();

    bf16x8 af[2];
#pragma unroll
    for (int kh = 0; kh < 2; ++kh)
      af[kh] = ld_frag(&f_s[(16 * w + q16) * FS_STR + 32 * kh + quad * 8]);

#pragma unroll
    for (int ot = 0; ot < 2; ++ot) {
#pragma unroll
      for (int kh = 0; kh < 2; ++kh) {
        const bf16x8 wf =
            w_frag(W + (size_t)(16 * ot + q16) * CH + c0 + 32 * kh + quad * 8);
        acc[ot] = __builtin_amdgcn_mfma_f32_16x16x32_bf16(af[kh], wf, acc[ot], 0, 0, 0);
      }
    }
    __syncthreads();
  }

  // C-layout: row n = 16w + quad*4 + r, col o = 16ot + q16
#pragma unroll
  for (int r = 0; r < 4; ++r) {
    const size_t row = (size_t)b * HWPIX + n0 + 16 * w + quad * 4 + r;
    outT[row * CQK_ + q16]      = (__bf16)(acc[0][r] + bo0);
    outT[row * CQK_ + 16 + q16] = (__bf16)(acc[1][r] + bo1);
  }
}

// ---- V projection (MFMA): outv[b][c][hw] bf16.
// grid (64 n-tiles, 4 c-tiles, 8 b), block 256 = 4 waves; wave w: c rows cbase+16w+[0,16).
__global__ __launch_bounds__(256) void proj_v_mfma(
    const float* __restrict__ f, const float* __restrict__ W,
    const float* __restrict__ bias, __bf16* __restrict__ outv)
{
  __shared__ __align__(16) __bf16 f_s[64 * FS_STR];  // [n][cin] transposed tile
  const int t     = threadIdx.x;
  const int w     = __builtin_amdgcn_readfirstlane(t >> 6);
  const int lane  = t & 63;
  const int q16   = lane & 15;
  const int quad  = lane >> 4;
  const int b     = blockIdx.z;
  const int n0    = blockIdx.x * 64;
  const int cbase = blockIdx.y * 64;
  const float* fb = f + (size_t)b * CH * HWPIX + n0;
  const int crow  = cbase + 16 * w + q16;  // A-fragment row (c)

  f32x4 acc[4];
#pragma unroll
  for (int nt = 0; nt < 4; ++nt) acc[nt] = (f32x4){0.f, 0.f, 0.f, 0.f};

  for (int c0 = 0; c0 < CH; c0 += 64) {
    {
      const int n  = t & 63;
      const int cp = (t >> 6) * 2;
#pragma unroll
      for (int k = 0; k < 8; ++k) {
        const int cin = cp + k * 8;
        bf16x2 pk;
        pk[0] = (__bf16)fb[(size_t)(c0 + cin) * HWPIX + n];
        pk[1] = (__bf16)fb[(size_t)(c0 + cin + 1) * HWPIX + n];
        *(bf16x2*)&f_s[n * FS_STR + cin] = pk;
      }
    }
    __syncthreads();

    bf16x8 af[2];
#pragma unroll
    for (int kh = 0; kh < 2; ++kh)
      af[kh] = w_frag(W + (size_t)crow * CH + c0 + 32 * kh + quad * 8);

#pragma unroll
    for (int nt = 0; nt < 4; ++nt) {
#pragma unroll
      for (int kh = 0; kh < 2; ++kh) {
        const bf16x8 bfr = ld_frag(&f_s[(16 * nt + q16) * FS_STR + 32 * kh + quad * 8]);
        acc[nt] = __builtin_amdgcn_mfma_f32_16x16x32_bf16(af[kh], bfr, acc[nt], 0, 0, 0);
      }
    }
    __syncthreads();
  }

  // C-layout: row c = cbase + 16w + quad*4 + r, col n = n0 + 16nt + q16
  const float4 bi = *(const float4*)&bias[cbase + 16 * w + quad * 4];
#pragma unroll
  for (int nt = 0; nt < 4; ++nt) {
#pragma unroll
    for (int r = 0; r < 4; ++r) {
      const int c = cbase + 16 * w + quad * 4 + r;
      outv[((size_t)b * CH + c) * HWPIX + n0 + 16 * nt + q16] =
          (__bf16)(acc[nt][r] + ((const float*)&bi)[r]);
    }
  }
}

// ---- Fused attention, MFMA 16x16x32 bf16, no-max online softmax (sum only).
// grid 512: b = bx&7 (XCD-pinned), q-tile = bx>>3 (64 q). block 256 = 4 waves.
// Wave w: score rows q in [16w,16w+16); AV channels c in [64w, 64w+64).
__global__ __launch_bounds__(256, 2) void attn_kernel(
    const __bf16* __restrict__ qT, const __bf16* __restrict__ kT,
    const __bf16* __restrict__ vv, float* __restrict__ out)
{
  __shared__ __align__(16) __bf16 p_s[64 * 72];  // [q][m], stride 72 bf16
  __shared__ float L_s[64];

  const int t    = threadIdx.x;
  const int w    = __builtin_amdgcn_readfirstlane(t >> 6);
  const int lane = t & 63;
  const int q16  = lane & 15;
  const int quad = lane >> 4;

  const int b  = blockIdx.x & 7;
  const int q0 = (blockIdx.x >> 3) * 64;

  const __bf16* kTb = kT + (size_t)b * HWPIX * CQK_;
  const __bf16* vbp = vv + ((size_t)b * CH + 64 * w) * HWPIX;

  // Q A-fragment, loaded once: Q[q = q0+16w+q16][c = quad*8 + j]
  const bf16x8 qfrag =
      *(const bf16x8*)(qT + ((size_t)b * HWPIX + q0 + 16 * w + q16) * CQK_ + quad * 8);

  f32x4 oacc[4][4];
#pragma unroll
  for (int i = 0; i < 4; ++i)
#pragma unroll
    for (int j = 0; j < 4; ++j)
      oacc[i][j] = (f32x4){0.f, 0.f, 0.f, 0.f};
  float Lp[4] = {0.f, 0.f, 0.f, 0.f};

  // K B-fragments for m0 = 0 (prefetched; rotated each iteration)
  bf16x8 kf[4];
#pragma unroll
  for (int mt = 0; mt < 4; ++mt)
    kf[mt] = *(const bf16x8*)(kTb + (size_t)(16 * mt + q16) * CQK_ + quad * 8);

  for (int m0 = 0; m0 < HWPIX; m0 += 64) {
    // ---- scores: S[16q x 16m] per mt, one MFMA each (K-dim = 32 = CQK)
    f32x4 S[4];
#pragma unroll
    for (int mt = 0; mt < 4; ++mt)
      S[mt] = __builtin_amdgcn_mfma_f32_16x16x32_bf16(
          qfrag, kf[mt], (f32x4){0.f, 0.f, 0.f, 0.f}, 0, 0, 0);

    // ---- V A-fragments for this m-tile (global, L2-resident; issued early)
    bf16x8 vf[4][2];
#pragma unroll
    for (int ct = 0; ct < 4; ++ct)
#pragma unroll
      for (int mh = 0; mh < 2; ++mh)
        vf[ct][mh] = *(const bf16x8*)(vbp + (size_t)(16 * ct + q16) * HWPIX
                                      + m0 + 32 * mh + quad * 8);

    // ---- exp, accumulate L, write P tile to LDS (bf16)
#pragma unroll
    for (int mt = 0; mt < 4; ++mt) {
#pragma unroll
      for (int r = 0; r < 4; ++r) {
        const float e = __expf(S[mt][r]);
        Lp[r] += e;
        p_s[(16 * w + quad * 4 + r) * 72 + 16 * mt + q16] = (__bf16)e;
      }
    }
    __syncthreads();

    // prefetch next iteration's K fragments (wraps harmlessly on last iter)
    const int mn = (m0 + 64) & (HWPIX - 1);
#pragma unroll
    for (int mt = 0; mt < 4; ++mt)
      kf[mt] = *(const bf16x8*)(kTb + (size_t)(mn + 16 * mt + q16) * CQK_ + quad * 8);

    // ---- P B-fragments from LDS: P[q = 16nt+q16][m = 32mh + quad*8 + j]
    bf16x8 pf[4][2];
#pragma unroll
    for (int nt = 0; nt < 4; ++nt)
#pragma unroll
      for (int mh = 0; mh < 2; ++mh)
        pf[nt][mh] = *(const bf16x8*)(&p_s[(16 * nt + q16) * 72 + 32 * mh + quad * 8]);

    // ---- AV: oacc[ct][nt] += V[16c x 32m] @ P^T[32m x 16q]
#pragma unroll
    for (int ct = 0; ct < 4; ++ct)
#pragma unroll
      for (int nt = 0; nt < 4; ++nt)
#pragma unroll
        for (int mh = 0; mh < 2; ++mh)
          oacc[ct][nt] = __builtin_amdgcn_mfma_f32_16x16x32_bf16(
              vf[ct][mh], pf[nt][mh], oacc[ct][nt], 0, 0, 0);
    __syncthreads();
  }

  // ---- finalize L: reduce partial sums across the 16 lanes of each row
#pragma unroll
  for (int r = 0; r < 4; ++r) {
    Lp[r] += __shfl_xor(Lp[r], 1);
    Lp[r] += __shfl_xor(Lp[r], 2);
    Lp[r] += __shfl_xor(Lp[r], 4);
    Lp[r] += __shfl_xor(Lp[r], 8);
  }
  if (q16 == 0) {
#pragma unroll
    for (int r = 0; r < 4; ++r) L_s[16 * w + quad * 4 + r] = Lp[r];
  }
  __syncthreads();

  float rinv[4];
#pragma unroll
  for (int nt = 0; nt < 4; ++nt) rinv[nt] = 1.0f / L_s[16 * nt + q16];

  float* ob = out + ((size_t)b * CH + 64 * w) * HWPIX + q0;
#pragma unroll
  for (int ct = 0; ct < 4; ++ct)
#pragma unroll
    for (int r = 0; r < 4; ++r)
#pragma unroll
      for (int nt = 0; nt < 4; ++nt)
        ob[(size_t)(16 * ct + quad * 4 + r) * HWPIX + 16 * nt + q16] =
            oacc[ct][nt][r] * rinv[nt];
}

extern "C" void kernel_launch(void* const* d_in, const int* in_sizes, int n_in,
                              void* d_out, int out_size, void* d_ws, size_t ws_size,
                              hipStream_t stream)
{
  const float* f1 = (const float*)d_in[0];
  const float* f2 = (const float*)d_in[1];
  const float* f3 = (const float*)d_in[2];
  const float* wq = (const float*)d_in[3];
  const float* bq = (const float*)d_in[4];
  const float* wk = (const float*)d_in[5];
  const float* bk = (const float*)d_in[6];
  const float* wv = (const float*)d_in[7];
  const float* bv = (const float*)d_in[8];
  float* outp = (float*)d_out;

  // workspace: qT [8][4096][32] | kT [8][4096][32] | v [8][256][4096]  (bf16, 20 MB)
  __bf16* qTw = (__bf16*)d_ws;
  __bf16* kTw = qTw + (size_t)BATCH * HWPIX * CQK_;
  __bf16* vw  = kTw + (size_t)BATCH * HWPIX * CQK_;

  proj_qk_mfma<<<dim3(64, 8), 256, 0, stream>>>(f1, wq, bq, qTw);
  proj_qk_mfma<<<dim3(64, 8), 256, 0, stream>>>(f2, wk, bk, kTw);
  proj_v_mfma <<<dim3(64, 4, 8), 256, 0, stream>>>(f3, wv, bv, vw);
  attn_kernel <<<dim3(512), 256, 0, stream>>>(qTw, kTw, vw, outp);
}